// Round 14
// baseline (142.088 us; speedup 1.0000x reference)
//
#include <hip/hip_runtime.h>
#include <hip/hip_bf16.h>
#include <math.h>

constexpr int B  = 8;
constexpr int C  = 256;
constexpr int L  = 16384;
constexpr int CH = 64;    // c = C/4
constexpr int NB = 256;   // L / BL

typedef __attribute__((ext_vector_type(8))) short bf16x8;
typedef __attribute__((ext_vector_type(4))) float f32x4;
typedef __attribute__((ext_vector_type(4))) unsigned u32x4;

__device__ __forceinline__ unsigned short f2bfu(float f) {
    __hip_bfloat16 h = __float2bfloat16(f);   // RNE, HW v_cvt
    return __builtin_bit_cast(unsigned short, h);
}
__device__ __forceinline__ unsigned pk2(float lo, float hi) {
    return (unsigned)f2bfu(lo) | ((unsigned)f2bfu(hi) << 16);
}
__device__ __forceinline__ bf16x8 pack8(const float* __restrict__ p) {
    float4 f0 = *(const float4*)p;
    float4 f1 = *(const float4*)(p + 4);
    uint4 u;
    u.x = pk2(f0.x, f0.y); u.y = pk2(f0.z, f0.w);
    u.z = pk2(f1.x, f1.y); u.w = pk2(f1.z, f1.w);
    return __builtin_bit_cast(bf16x8, u);
}
__device__ __forceinline__ f32x4 mfma16(bf16x8 a, bf16x8 b, f32x4 c) {
    return __builtin_amdgcn_mfma_f32_16x16x32_bf16(a, b, c, 0, 0, 0);
}

// fire-and-forget global->LDS DMA, 16B/lane (1 KB per wave-instruction)
__device__ __forceinline__ void dma16(const float* g, float* l) {
    __builtin_amdgcn_global_load_lds(
        (const __attribute__((address_space(1))) void*)g,
        (__attribute__((address_space(3))) void*)l, 16, 0, 0);
}

// ---------------------------------------------------------------------------
// Kernel 1: q/k/v via MFMA.  grid (L/256, B) = (64,8), block 256 (4 waves).
// Identical structure to r11/r13 (passing); W now converted inline (pack8)
// from LLC-hot fp32 — wcvt kernel removed.
// ---------------------------------------------------------------------------
__global__ __launch_bounds__(256, 2) void qkv_mfma(
    const float* __restrict__ x1, const float* __restrict__ x2,
    const float* __restrict__ Wq, const float* __restrict__ Wk,
    const float* __restrict__ Wv,
    const float* __restrict__ bq, const float* __restrict__ bk,
    const float* __restrict__ bv,
    unsigned short* __restrict__ qt, unsigned short* __restrict__ kt,
    unsigned short* __restrict__ vt)
{
    __shared__ float xbuf[2][32 * 256];   // 2 x 32 KB
    const int t    = threadIdx.x;
    const int b    = blockIdx.y;
    const int pos0 = blockIdx.x * 256;
    const int w    = t >> 6;
    const int lane = t & 63;
    const int g    = lane >> 4;
    const int l15  = lane & 15;

    const float* x1b = x1 + (size_t)b * C * L + pos0;
    const float* x2b = x2 + (size_t)b * C * L + pos0;

    // source slot pre-rotation: rows clocal = w*8..w*8+7 all have R = 2w
    const int srcslot = (lane + 64 - 2 * w) & 63;

    // stage chunk ck (0..15): 8 DMA instructions per wave
    auto stage = [&](int ck) {
        const float* src = (ck < 8) ? x1b : x2b;
        const int cb = (ck & 7) * 32;
        float* dst = xbuf[ck & 1];
#pragma unroll
        for (int i = 0; i < 8; ++i) {
            const int clocal = w * 8 + i;
            dma16(src + (size_t)(cb + clocal) * L + srcslot * 4,
                  dst + clocal * 256);
        }
    };

    // read-side fragment build: pos subtile st, k-group g -> bf16x8
    auto bfrag = [&](const float* bs, int st) -> bf16x8 {
        const int slot = (w * 16 + st * 4 + (l15 >> 2) + 2 * g) & 63;
        const int fb0  = (g * 8) * 256 + slot * 4 + (l15 & 3);
        float f0 = bs[fb0 + 0 * 256], f1 = bs[fb0 + 1 * 256];
        float f2 = bs[fb0 + 2 * 256], f3 = bs[fb0 + 3 * 256];
        float f4 = bs[fb0 + 4 * 256], f5 = bs[fb0 + 5 * 256];
        float f6 = bs[fb0 + 6 * 256], f7 = bs[fb0 + 7 * 256];
        uint4 u;
        u.x = pk2(f0, f1); u.y = pk2(f2, f3);
        u.z = pk2(f4, f5); u.w = pk2(f6, f7);
        return __builtin_bit_cast(bf16x8, u);
    };

    f32x4 accq[4][4], acck[4][4];
#pragma unroll
    for (int ot = 0; ot < 4; ++ot)
#pragma unroll
        for (int st = 0; st < 4; ++st) {
            accq[ot][st] = (f32x4){0.f, 0.f, 0.f, 0.f};
            acck[ot][st] = (f32x4){0.f, 0.f, 0.f, 0.f};
        }

    stage(0);
    __syncthreads();

    // ---- x1 chunks: q, k ----
#pragma unroll 1
    for (int ck = 0; ck < 8; ++ck) {
        stage(ck + 1);
        bf16x8 aq[4], ak[4];
#pragma unroll
        for (int ot = 0; ot < 4; ++ot) {
            const size_t wr = (size_t)(ot * 16 + l15) * 256 + ck * 32 + g * 8;
            aq[ot] = pack8(Wq + wr);
            ak[ot] = pack8(Wk + wr);
        }
        const float* bs = xbuf[ck & 1];
#pragma unroll
        for (int st = 0; st < 4; ++st) {
            const bf16x8 bx = bfrag(bs, st);
#pragma unroll
            for (int ot = 0; ot < 4; ++ot) {
                accq[ot][st] = mfma16(aq[ot], bx, accq[ot][st]);
                acck[ot][st] = mfma16(ak[ot], bx, acck[ot][st]);
            }
        }
        __syncthreads();
    }

    // ---- store q, k ([b][pos][och]) ----
#pragma unroll
    for (int ot = 0; ot < 4; ++ot) {
        const f32x4 bq4 = *(const f32x4*)(bq + ot * 16 + g * 4);
        const f32x4 bk4 = *(const f32x4*)(bk + ot * 16 + g * 4);
#pragma unroll
        for (int st = 0; st < 4; ++st) {
            const int pos = pos0 + w * 64 + st * 16 + l15;
            uint2 vq, vk;
            vq.x = pk2(accq[ot][st][0] + bq4[0], accq[ot][st][1] + bq4[1]);
            vq.y = pk2(accq[ot][st][2] + bq4[2], accq[ot][st][3] + bq4[3]);
            *(uint2*)(qt + ((size_t)b * L + pos) * 64 + ot * 16 + g * 4) = vq;
            vk.x = pk2(acck[ot][st][0] + bk4[0], acck[ot][st][1] + bk4[1]);
            vk.y = pk2(acck[ot][st][2] + bk4[2], acck[ot][st][3] + bk4[3]);
            *(uint2*)(kt + ((size_t)b * L + pos) * 64 + ot * 16 + g * 4) = vk;
        }
    }

    // ---- x2 chunks: v ----
    f32x4 accv[4][4];
#pragma unroll
    for (int ot = 0; ot < 4; ++ot)
#pragma unroll
        for (int st = 0; st < 4; ++st) accv[ot][st] = (f32x4){0.f, 0.f, 0.f, 0.f};

#pragma unroll 1
    for (int ck = 8; ck < 16; ++ck) {
        if (ck < 15) stage(ck + 1);
        bf16x8 av[4];
#pragma unroll
        for (int ot = 0; ot < 4; ++ot)
            av[ot] = pack8(Wv + (size_t)(ot * 16 + l15) * 256 +
                           (ck - 8) * 32 + g * 8);
        const float* bs = xbuf[ck & 1];
#pragma unroll
        for (int st = 0; st < 4; ++st) {
            const bf16x8 bx = bfrag(bs, st);
#pragma unroll
            for (int ot = 0; ot < 4; ++ot)
                accv[ot][st] = mfma16(av[ot], bx, accv[ot][st]);
        }
        if (ck < 15) __syncthreads();
    }

    // ---- store v ([b][och][pos]) ----
#pragma unroll
    for (int ot = 0; ot < 4; ++ot) {
        const f32x4 bv4 = *(const f32x4*)(bv + ot * 16 + g * 4);
#pragma unroll
        for (int st = 0; st < 4; ++st) {
            const int pos = pos0 + w * 64 + st * 16 + l15;
#pragma unroll
            for (int r = 0; r < 4; ++r)
                vt[((size_t)b * CH + ot * 16 + g * 4 + r) * L + pos] =
                    f2bfu(accv[ot][st][r] + bv4[r]);
        }
    }
}

// ---------------------------------------------------------------------------
// Kernel 2: windowed attention, all-MFMA.  grid 2048 (i = n*8 + b), block 256.
// q from scrambled (bqi=i>>8, nqi=i&255).
// r14: (a) Wo converted inline from fp32; (b) epilogue transposes the
// 256o x 64pos fp32 tile through LDS (overlaying the dead staging buffers,
// XOR col^((o>>2&3)<<4)) so out-stores are 256B-contiguous nt f32x4.
// ---------------------------------------------------------------------------
__global__ __launch_bounds__(256) void attn_mfma(
    const unsigned short* __restrict__ qt, const unsigned short* __restrict__ kt,
    const unsigned short* __restrict__ vt, const float* __restrict__ mask,
    const float* __restrict__ Wo, const float* __restrict__ bo,
    float* __restrict__ outp)
{
    __shared__ __align__(16) char smem[65536];
    unsigned short* qs  = (unsigned short*)(smem);           //  8 KB [64][64]
    unsigned short* ks2 = (unsigned short*)(smem + 8192);    // 16 KB [128][64]
    unsigned short* vs  = (unsigned short*)(smem + 24576);   // 16 KB [64][128]
    unsigned short* ps  = (unsigned short*)(smem + 40960);   // 16 KB [64][128]
    unsigned short* aos = (unsigned short*)(smem + 57344);   //  8 KB [64][64]

    const int i   = blockIdx.x;
    const int b   = i & 7;
    const int n   = i >> 3;
    const int bqi = i >> 8;
    const int nqi = i & 255;
    const int t    = threadIdx.x;
    const int lane = t & 63;
    const int w    = t >> 6;
    const int g    = lane >> 4;
    const int l15  = lane & 15;
    const int jbase = n * 64 - 64;

    // ---- stage q (64 rows x 128B), nontemporal (read exactly once) ----
    {
        const char* src = (const char*)(qt + ((size_t)bqi * L + nqi * 64) * 64);
#pragma unroll
        for (int it = 0; it < 2; ++it) {
            const int row = (t >> 3) + it * 32, ch = t & 7;
            u32x4 d = __builtin_nontemporal_load(
                (const u32x4*)(src + row * 128 + ch * 16));
            *(u32x4*)((char*)qs + row * 128 + ((ch ^ (row & 7)) << 4)) = d;
        }
    }
    // ---- stage k window (128 rows x 128B), zero pad rows for n==0 ----
    {
#pragma unroll
        for (int it = 0; it < 4; ++it) {
            const int row = (t >> 3) + it * 32, ch = t & 7;
            uint4 d = make_uint4(0u, 0u, 0u, 0u);
            if (!(n == 0 && row < 64))
                d = *(const uint4*)((const char*)(kt + ((size_t)b * L + jbase + row) * 64) + ch * 16);
            *(uint4*)((char*)ks2 + row * 128 + ((ch ^ (row & 7)) << 4)) = d;
        }
    }
    // ---- stage v window (64 rows x 256B), zero first-half cols for n==0 ----
    {
#pragma unroll
        for (int it = 0; it < 4; ++it) {
            const int row = (t >> 4) + it * 16, ch = t & 15;
            uint4 d = make_uint4(0u, 0u, 0u, 0u);
            if (!(n == 0 && ch < 8))
                d = *(const uint4*)((const char*)(vt + ((size_t)b * CH + row) * L + jbase) + ch * 16);
            *(uint4*)((char*)vs + row * 256 + ((ch ^ (row & 7)) << 4)) = d;
        }
    }
    __syncthreads();

    // ---- E = q^T k ----
    f32x4 ae[8];
#pragma unroll
    for (int jt = 0; jt < 8; ++jt) ae[jt] = (f32x4){0.f, 0.f, 0.f, 0.f};
    bf16x8 qa[2];
#pragma unroll
    for (int ks = 0; ks < 2; ++ks) {
        const int row = w * 16 + l15;
        qa[ks] = *(const bf16x8*)((char*)qs + row * 128 + (((ks * 4 + g) ^ (row & 7)) << 4));
    }
#pragma unroll
    for (int jt = 0; jt < 8; ++jt) {
#pragma unroll
        for (int ks = 0; ks < 2; ++ks) {
            const int row = jt * 16 + l15;
            const bf16x8 kb = *(const bf16x8*)((char*)ks2 + row * 128 + (((ks * 4 + g) ^ (row & 7)) << 4));
            ae[jt] = mfma16(qa[ks], kb, ae[jt]);
        }
    }

    // ---- softmax: e = E/8 + log(fm+1e-6) ----
    const float* mrow = mask + (size_t)b * L + jbase;
    float pw8[8];
#pragma unroll
    for (int jt = 0; jt < 8; ++jt) {
        const int j = l15 + jt * 16;
        pw8[jt] = (n == 0 && j < 64) ? 0.f : mrow[j];
    }
    const int ii0 = w * 16 + g * 4;
#pragma unroll
    for (int jt = 0; jt < 8; ++jt) {
        const int j = l15 + jt * 16;
#pragma unroll
        for (int r = 0; r < 4; ++r) {
            const float fm = (j >= ii0 + r && j < ii0 + r + 64) ? pw8[jt] : 0.f;
            ae[jt][r] = ae[jt][r] * 0.125f + __logf(fm + 1e-6f);
        }
    }
    f32x4 mx, inv;
#pragma unroll
    for (int r = 0; r < 4; ++r) {
        float m = ae[0][r];
#pragma unroll
        for (int jt = 1; jt < 8; ++jt) m = fmaxf(m, ae[jt][r]);
        m = fmaxf(m, __shfl_xor(m, 1));
        m = fmaxf(m, __shfl_xor(m, 2));
        m = fmaxf(m, __shfl_xor(m, 4));
        m = fmaxf(m, __shfl_xor(m, 8));
        mx[r] = m;
    }
    f32x4 sum = {0.f, 0.f, 0.f, 0.f};
#pragma unroll
    for (int jt = 0; jt < 8; ++jt)
#pragma unroll
        for (int r = 0; r < 4; ++r) {
            const float p = __expf(ae[jt][r] - mx[r]);
            ae[jt][r] = p;
            sum[r] += p;
        }
#pragma unroll
    for (int r = 0; r < 4; ++r) {
        float s = sum[r];
        s += __shfl_xor(s, 1);
        s += __shfl_xor(s, 2);
        s += __shfl_xor(s, 4);
        s += __shfl_xor(s, 8);
        inv[r] = 1.0f / s;
    }
#pragma unroll
    for (int jt = 0; jt < 8; ++jt) {
        const int j = l15 + jt * 16;
#pragma unroll
        for (int r = 0; r < 4; ++r) {
            const float fm = (j >= ii0 + r && j < ii0 + r + 64) ? pw8[jt] : 0.f;
            const float p = ae[jt][r] * inv[r] * fm;
            const int lrow = w * 16 + g * 4 + r;
            *(unsigned short*)((char*)ps + lrow * 256 +
                (((j >> 3) ^ (lrow & 7)) << 4) + (j & 7) * 2) = f2bfu(p);
        }
    }

    // ---- AO^T[l][c] = att[l][:] x v[c][:] ----
    f32x4 ao[4];
#pragma unroll
    for (int ct = 0; ct < 4; ++ct) ao[ct] = (f32x4){0.f, 0.f, 0.f, 0.f};
#pragma unroll
    for (int ks = 0; ks < 4; ++ks) {
        const int arow = w * 16 + l15;
        const int aq_ = ks * 4 + g;
        const bf16x8 pa = *(const bf16x8*)((char*)ps + arow * 256 + ((aq_ ^ (arow & 7)) << 4));
#pragma unroll
        for (int ct = 0; ct < 4; ++ct) {
            const int vrow = ct * 16 + l15;
            const bf16x8 vb = *(const bf16x8*)((char*)vs + vrow * 256 + ((aq_ ^ (vrow & 7)) << 4));
            ao[ct] = mfma16(pa, vb, ao[ct]);
        }
    }
#pragma unroll
    for (int ct = 0; ct < 4; ++ct)
#pragma unroll
        for (int r = 0; r < 4; ++r) {
            const int lr = w * 16 + g * 4 + r;
            const int c  = ct * 16 + l15;
            *(unsigned short*)((char*)aos + lr * 128 +
                (((c >> 3) ^ (lr & 7)) << 4) + (c & 7) * 2) = f2bfu(fmaxf(ao[ct][r], 0.f));
        }
    __syncthreads();

    // ---- out = Wo @ relu(AO) + bo, * mask ----
    f32x4 mvv;
#pragma unroll
    for (int lt = 0; lt < 4; ++lt)
        mvv[lt] = mask[(size_t)b * L + n * 64 + lt * 16 + l15];

    bf16x8 bbs[8];
#pragma unroll
    for (int ks = 0; ks < 2; ++ks)
#pragma unroll
        for (int lt = 0; lt < 4; ++lt) {
            const int brow = lt * 16 + l15;
            bbs[ks * 4 + lt] = *(const bf16x8*)((char*)aos + brow * 128 +
                (((ks * 4 + g) ^ (brow & 7)) << 4));
        }
    __syncthreads();   // all staging-buffer reads done; smem reusable as outT

    // outT[256 o][64 col] fp32, col XOR-swizzled by ((o>>2)&3)<<4 (2-way, free)
    float* outT = (float*)smem;

#pragma unroll 1
    for (int ot = 0; ot < 4; ++ot) {
        const int orow = ot * 64 + w * 16 + l15;
        bf16x8 wa[2];
#pragma unroll
        for (int ks = 0; ks < 2; ++ks)
            wa[ks] = pack8(Wo + (size_t)orow * 64 + ks * 32 + g * 8);
        f32x4 acw[4];
#pragma unroll
        for (int lt = 0; lt < 4; ++lt) acw[lt] = (f32x4){0.f, 0.f, 0.f, 0.f};
#pragma unroll
        for (int ks = 0; ks < 2; ++ks)
#pragma unroll
            for (int lt = 0; lt < 4; ++lt)
                acw[lt] = mfma16(wa[ks], bbs[ks * 4 + lt], acw[lt]);
        const f32x4 bo4 = *(const f32x4*)(bo + ot * 64 + w * 16 + g * 4);
#pragma unroll
        for (int lt = 0; lt < 4; ++lt)
#pragma unroll
            for (int r = 0; r < 4; ++r) {
                const int ol  = ot * 64 + w * 16 + g * 4 + r;
                const int col = lt * 16 + l15;
                outT[ol * 64 + (col ^ (((ol >> 2) & 3) << 4))] =
                    (acw[lt][r] + bo4[r]) * mvv[lt];
            }
    }
    __syncthreads();

    // ---- coalesced nt store: per instr, 4 x 256B contiguous segments ----
    float* outb = outp + (size_t)b * C * L + n * 64;
#pragma unroll
    for (int it2 = 0; it2 < 16; ++it2) {
        const int f  = it2 * 256 + t;
        const int o  = f >> 4;            // 0..255
        const int pq = (f & 15) * 4;      // 0..60
        const int sw = ((o >> 2) & 3) << 4;
        const f32x4 v4 = *(const f32x4*)(outT + o * 64 + (pq ^ sw));
        __builtin_nontemporal_store(v4, (f32x4*)(outb + (size_t)o * L + pq));
    }
}

// ---------------------------------------------------------------------------
extern "C" void kernel_launch(void* const* d_in, const int* in_sizes, int n_in,
                              void* d_out, int out_size, void* d_ws, size_t ws_size,
                              hipStream_t stream) {
    const float* x1   = (const float*)d_in[0];
    const float* x2   = (const float*)d_in[1];
    const float* mask = (const float*)d_in[2];
    const float* Wq   = (const float*)d_in[3];
    const float* bq   = (const float*)d_in[4];
    const float* Wk   = (const float*)d_in[5];
    const float* bk   = (const float*)d_in[6];
    const float* Wv   = (const float*)d_in[7];
    const float* bv   = (const float*)d_in[8];
    const float* Wo   = (const float*)d_in[9];
    const float* bo   = (const float*)d_in[10];
    float* out = (float*)d_out;

    unsigned short* ws = (unsigned short*)d_ws;
    const size_t PL = (size_t)B * L * CH;
    unsigned short* qt = ws;
    unsigned short* kt = qt + PL;
    unsigned short* vt = kt + PL;
    const size_t need = 3 * PL * sizeof(unsigned short);
    if (ws_size < need) {
        (void)hipMemsetAsync(d_out, 0, (size_t)out_size * sizeof(float), stream);
        return;
    }

    qkv_mfma<<<dim3(L / 256, B), 256, 0, stream>>>(
        x1, x2, Wq, Wk, Wv, bq, bk, bv, qt, kt, vt);

    attn_mfma<<<dim3(NB * B), 256, 0, stream>>>(
        qt, kt, vt, mask, Wo, bo, out);
}

// Round 15
// 120.707 us; speedup vs baseline: 1.1771x; 1.1771x over previous
//
#include <hip/hip_runtime.h>
#include <hip/hip_bf16.h>
#include <math.h>

constexpr int B  = 8;
constexpr int C  = 256;
constexpr int L  = 16384;
constexpr int CH = 64;    // c = C/4
constexpr int NB = 256;   // L / BL

typedef __attribute__((ext_vector_type(8))) short bf16x8;
typedef __attribute__((ext_vector_type(4))) float f32x4;
typedef __attribute__((ext_vector_type(4))) unsigned u32x4;

__device__ __forceinline__ unsigned short f2bfu(float f) {
    __hip_bfloat16 h = __float2bfloat16(f);   // RNE, HW v_cvt
    return __builtin_bit_cast(unsigned short, h);
}
__device__ __forceinline__ unsigned pk2(float lo, float hi) {
    return (unsigned)f2bfu(lo) | ((unsigned)f2bfu(hi) << 16);
}
__device__ __forceinline__ f32x4 mfma16(bf16x8 a, bf16x8 b, f32x4 c) {
    return __builtin_amdgcn_mfma_f32_16x16x32_bf16(a, b, c, 0, 0, 0);
}

// fire-and-forget global->LDS DMA, 16B/lane (1 KB per wave-instruction)
__device__ __forceinline__ void dma16(const float* g, float* l) {
    __builtin_amdgcn_global_load_lds(
        (const __attribute__((address_space(1))) void*)g,
        (__attribute__((address_space(3))) void*)l, 16, 0, 0);
}

// ---------------------------------------------------------------------------
// Kernel 0: convert Wq,Wk,Wv,Wo (each 16384 fp32) to bf16 once.
// ---------------------------------------------------------------------------
__global__ __launch_bounds__(256) void wcvt_kernel(
    const float* __restrict__ Wq, const float* __restrict__ Wk,
    const float* __restrict__ Wv, const float* __restrict__ Wo,
    unsigned short* __restrict__ dst)   // [4][16384]
{
    const int z = blockIdx.y;
    const float* src = (z == 0) ? Wq : (z == 1) ? Wk : (z == 2) ? Wv : Wo;
    const int i = (blockIdx.x * 256 + threadIdx.x) * 4;
    float4 f = *(const float4*)(src + i);
    uint2 v;
    v.x = pk2(f.x, f.y);
    v.y = pk2(f.z, f.w);
    *(uint2*)(dst + (size_t)z * 16384 + i) = v;
}

// ---------------------------------------------------------------------------
// Kernel 1: q/k/v via MFMA.  grid (L/256, B) = (64,8), block 256 (4 waves).
// 256-pos tile; 16 chunks of 32 c (8 from x1 -> q,k; 8 from x2 -> v).
// Staging: global_load_lds 16B/lane, one 1KB c-row per instruction, source
// pre-rotated by R=2w slots so read-side is 2-way (free).
// LDS: fp32 [32 c][256 pos] x 2 buffers = 64 KB.  Chunk pipeline: issue
// DMA(k+1), compute(k), __syncthreads.
// Outputs: q,k transposed [b][pos][och] bf16;  v natural [b][och][pos] bf16.
// ---------------------------------------------------------------------------
__global__ __launch_bounds__(256, 2) void qkv_mfma(
    const float* __restrict__ x1, const float* __restrict__ x2,
    const unsigned short* __restrict__ wqb, const unsigned short* __restrict__ wkb,
    const unsigned short* __restrict__ wvb,
    const float* __restrict__ bq, const float* __restrict__ bk,
    const float* __restrict__ bv,
    unsigned short* __restrict__ qt, unsigned short* __restrict__ kt,
    unsigned short* __restrict__ vt)
{
    __shared__ float xbuf[2][32 * 256];   // 2 x 32 KB
    const int t    = threadIdx.x;
    const int b    = blockIdx.y;
    const int pos0 = blockIdx.x * 256;
    const int w    = t >> 6;
    const int lane = t & 63;
    const int g    = lane >> 4;
    const int l15  = lane & 15;

    const float* x1b = x1 + (size_t)b * C * L + pos0;
    const float* x2b = x2 + (size_t)b * C * L + pos0;

    // source slot pre-rotation: rows clocal = w*8..w*8+7 all have R = 2w
    const int srcslot = (lane + 64 - 2 * w) & 63;

    // stage chunk ck (0..15): 8 DMA instructions per wave
    auto stage = [&](int ck) {
        const float* src = (ck < 8) ? x1b : x2b;
        const int cb = (ck & 7) * 32;
        float* dst = xbuf[ck & 1];
#pragma unroll
        for (int i = 0; i < 8; ++i) {
            const int clocal = w * 8 + i;
            dma16(src + (size_t)(cb + clocal) * L + srcslot * 4,
                  dst + clocal * 256);
        }
    };

    // read-side fragment build: pos subtile st, k-group g -> bf16x8
    // desired pos = w*64 + st*16 + l15  ->  global slot w*16 + st*4 + (l15>>2)
    // LDS slot = (global slot + 2g) & 63   (rows g*8..g*8+7 staged by wave g)
    auto bfrag = [&](const float* bs, int st) -> bf16x8 {
        const int slot = (w * 16 + st * 4 + (l15 >> 2) + 2 * g) & 63;
        const int fb0  = (g * 8) * 256 + slot * 4 + (l15 & 3);
        float f0 = bs[fb0 + 0 * 256], f1 = bs[fb0 + 1 * 256];
        float f2 = bs[fb0 + 2 * 256], f3 = bs[fb0 + 3 * 256];
        float f4 = bs[fb0 + 4 * 256], f5 = bs[fb0 + 5 * 256];
        float f6 = bs[fb0 + 6 * 256], f7 = bs[fb0 + 7 * 256];
        uint4 u;
        u.x = pk2(f0, f1); u.y = pk2(f2, f3);
        u.z = pk2(f4, f5); u.w = pk2(f6, f7);
        return __builtin_bit_cast(bf16x8, u);
    };

    f32x4 accq[4][4], acck[4][4];
#pragma unroll
    for (int ot = 0; ot < 4; ++ot)
#pragma unroll
        for (int st = 0; st < 4; ++st) {
            accq[ot][st] = (f32x4){0.f, 0.f, 0.f, 0.f};
            acck[ot][st] = (f32x4){0.f, 0.f, 0.f, 0.f};
        }

    stage(0);
    __syncthreads();

    // ---- x1 chunks: q, k ----
#pragma unroll 1
    for (int ck = 0; ck < 8; ++ck) {
        stage(ck + 1);
        bf16x8 aq[4], ak[4];
#pragma unroll
        for (int ot = 0; ot < 4; ++ot) {
            const size_t wr = (size_t)(ot * 16 + l15) * 256 + ck * 32 + g * 8;
            aq[ot] = *(const bf16x8*)(wqb + wr);
            ak[ot] = *(const bf16x8*)(wkb + wr);
        }
        const float* bs = xbuf[ck & 1];
#pragma unroll
        for (int st = 0; st < 4; ++st) {
            const bf16x8 bx = bfrag(bs, st);
#pragma unroll
            for (int ot = 0; ot < 4; ++ot) {
                accq[ot][st] = mfma16(aq[ot], bx, accq[ot][st]);
                acck[ot][st] = mfma16(ak[ot], bx, acck[ot][st]);
            }
        }
        __syncthreads();
    }

    // ---- store q, k ([b][pos][och]) ----
#pragma unroll
    for (int ot = 0; ot < 4; ++ot) {
        const f32x4 bq4 = *(const f32x4*)(bq + ot * 16 + g * 4);
        const f32x4 bk4 = *(const f32x4*)(bk + ot * 16 + g * 4);
#pragma unroll
        for (int st = 0; st < 4; ++st) {
            const int pos = pos0 + w * 64 + st * 16 + l15;
            uint2 vq, vk;
            vq.x = pk2(accq[ot][st][0] + bq4[0], accq[ot][st][1] + bq4[1]);
            vq.y = pk2(accq[ot][st][2] + bq4[2], accq[ot][st][3] + bq4[3]);
            *(uint2*)(qt + ((size_t)b * L + pos) * 64 + ot * 16 + g * 4) = vq;
            vk.x = pk2(acck[ot][st][0] + bk4[0], acck[ot][st][1] + bk4[1]);
            vk.y = pk2(acck[ot][st][2] + bk4[2], acck[ot][st][3] + bk4[3]);
            *(uint2*)(kt + ((size_t)b * L + pos) * 64 + ot * 16 + g * 4) = vk;
        }
    }

    // ---- x2 chunks: v ----
    f32x4 accv[4][4];
#pragma unroll
    for (int ot = 0; ot < 4; ++ot)
#pragma unroll
        for (int st = 0; st < 4; ++st) accv[ot][st] = (f32x4){0.f, 0.f, 0.f, 0.f};

#pragma unroll 1
    for (int ck = 8; ck < 16; ++ck) {
        if (ck < 15) stage(ck + 1);
        bf16x8 av[4];
#pragma unroll
        for (int ot = 0; ot < 4; ++ot)
            av[ot] = *(const bf16x8*)(wvb + (size_t)(ot * 16 + l15) * 256 +
                                      (ck - 8) * 32 + g * 8);
        const float* bs = xbuf[ck & 1];
#pragma unroll
        for (int st = 0; st < 4; ++st) {
            const bf16x8 bx = bfrag(bs, st);
#pragma unroll
            for (int ot = 0; ot < 4; ++ot)
                accv[ot][st] = mfma16(av[ot], bx, accv[ot][st]);
        }
        if (ck < 15) __syncthreads();
    }

    // ---- store v ([b][och][pos]) ----
#pragma unroll
    for (int ot = 0; ot < 4; ++ot) {
        const f32x4 bv4 = *(const f32x4*)(bv + ot * 16 + g * 4);
#pragma unroll
        for (int st = 0; st < 4; ++st) {
            const int pos = pos0 + w * 64 + st * 16 + l15;
#pragma unroll
            for (int r = 0; r < 4; ++r)
                vt[((size_t)b * CH + ot * 16 + g * 4 + r) * L + pos] =
                    f2bfu(accv[ot][st][r] + bv4[r]);
        }
    }
}

// ---------------------------------------------------------------------------
// Kernel 2: windowed attention, all-MFMA.  grid 2048 (i = n*8 + b), block 256.
// q from scrambled (bqi=i>>8, nqi=i&255).
// NONTEMPORAL q loads (read-once, via ext_vector u32x4) and NONTEMPORAL
// scalar out stores (never re-read).
// ---------------------------------------------------------------------------
__global__ __launch_bounds__(256) void attn_mfma(
    const unsigned short* __restrict__ qt, const unsigned short* __restrict__ kt,
    const unsigned short* __restrict__ vt, const float* __restrict__ mask,
    const unsigned short* __restrict__ wob, const float* __restrict__ bo,
    float* __restrict__ outp)
{
    __shared__ unsigned short qs [64 * 64];
    __shared__ unsigned short ks2[128 * 64];
    __shared__ unsigned short vs [64 * 128];
    __shared__ unsigned short ps [64 * 128];
    __shared__ unsigned short aos[64 * 64];

    const int i   = blockIdx.x;
    const int b   = i & 7;
    const int n   = i >> 3;
    const int bqi = i >> 8;
    const int nqi = i & 255;
    const int t    = threadIdx.x;
    const int lane = t & 63;
    const int w    = t >> 6;
    const int g    = lane >> 4;
    const int l15  = lane & 15;
    const int jbase = n * 64 - 64;

    // ---- stage q (64 rows x 128B), nontemporal (read exactly once) ----
    {
        const char* src = (const char*)(qt + ((size_t)bqi * L + nqi * 64) * 64);
#pragma unroll
        for (int it = 0; it < 2; ++it) {
            const int row = (t >> 3) + it * 32, ch = t & 7;
            u32x4 d = __builtin_nontemporal_load(
                (const u32x4*)(src + row * 128 + ch * 16));
            *(u32x4*)((char*)qs + row * 128 + ((ch ^ (row & 7)) << 4)) = d;
        }
    }
    // ---- stage k window (128 rows x 128B), zero pad rows for n==0 ----
    {
#pragma unroll
        for (int it = 0; it < 4; ++it) {
            const int row = (t >> 3) + it * 32, ch = t & 7;
            uint4 d = make_uint4(0u, 0u, 0u, 0u);
            if (!(n == 0 && row < 64))
                d = *(const uint4*)((const char*)(kt + ((size_t)b * L + jbase + row) * 64) + ch * 16);
            *(uint4*)((char*)ks2 + row * 128 + ((ch ^ (row & 7)) << 4)) = d;
        }
    }
    // ---- stage v window (64 rows x 256B), zero first-half cols for n==0 ----
    {
#pragma unroll
        for (int it = 0; it < 4; ++it) {
            const int row = (t >> 4) + it * 16, ch = t & 15;
            uint4 d = make_uint4(0u, 0u, 0u, 0u);
            if (!(n == 0 && ch < 8))
                d = *(const uint4*)((const char*)(vt + ((size_t)b * CH + row) * L + jbase) + ch * 16);
            *(uint4*)((char*)vs + row * 256 + ((ch ^ (row & 7)) << 4)) = d;
        }
    }
    __syncthreads();

    // ---- E = q^T k ----
    f32x4 ae[8];
#pragma unroll
    for (int jt = 0; jt < 8; ++jt) ae[jt] = (f32x4){0.f, 0.f, 0.f, 0.f};
    bf16x8 qa[2];
#pragma unroll
    for (int ks = 0; ks < 2; ++ks) {
        const int row = w * 16 + l15;
        qa[ks] = *(const bf16x8*)((char*)qs + row * 128 + (((ks * 4 + g) ^ (row & 7)) << 4));
    }
#pragma unroll
    for (int jt = 0; jt < 8; ++jt) {
#pragma unroll
        for (int ks = 0; ks < 2; ++ks) {
            const int row = jt * 16 + l15;
            const bf16x8 kb = *(const bf16x8*)((char*)ks2 + row * 128 + (((ks * 4 + g) ^ (row & 7)) << 4));
            ae[jt] = mfma16(qa[ks], kb, ae[jt]);
        }
    }

    // ---- softmax: e = E/8 + log(fm+1e-6) ----
    const float* mrow = mask + (size_t)b * L + jbase;
    float pw8[8];
#pragma unroll
    for (int jt = 0; jt < 8; ++jt) {
        const int j = l15 + jt * 16;
        pw8[jt] = (n == 0 && j < 64) ? 0.f : mrow[j];
    }
    const int ii0 = w * 16 + g * 4;
#pragma unroll
    for (int jt = 0; jt < 8; ++jt) {
        const int j = l15 + jt * 16;
#pragma unroll
        for (int r = 0; r < 4; ++r) {
            const float fm = (j >= ii0 + r && j < ii0 + r + 64) ? pw8[jt] : 0.f;
            ae[jt][r] = ae[jt][r] * 0.125f + __logf(fm + 1e-6f);
        }
    }
    f32x4 mx, inv;
#pragma unroll
    for (int r = 0; r < 4; ++r) {
        float m = ae[0][r];
#pragma unroll
        for (int jt = 1; jt < 8; ++jt) m = fmaxf(m, ae[jt][r]);
        m = fmaxf(m, __shfl_xor(m, 1));
        m = fmaxf(m, __shfl_xor(m, 2));
        m = fmaxf(m, __shfl_xor(m, 4));
        m = fmaxf(m, __shfl_xor(m, 8));
        mx[r] = m;
    }
    f32x4 sum = {0.f, 0.f, 0.f, 0.f};
#pragma unroll
    for (int jt = 0; jt < 8; ++jt)
#pragma unroll
        for (int r = 0; r < 4; ++r) {
            const float p = __expf(ae[jt][r] - mx[r]);
            ae[jt][r] = p;
            sum[r] += p;
        }
#pragma unroll
    for (int r = 0; r < 4; ++r) {
        float s = sum[r];
        s += __shfl_xor(s, 1);
        s += __shfl_xor(s, 2);
        s += __shfl_xor(s, 4);
        s += __shfl_xor(s, 8);
        inv[r] = 1.0f / s;
    }
#pragma unroll
    for (int jt = 0; jt < 8; ++jt) {
        const int j = l15 + jt * 16;
#pragma unroll
        for (int r = 0; r < 4; ++r) {
            const float fm = (j >= ii0 + r && j < ii0 + r + 64) ? pw8[jt] : 0.f;
            const float p = ae[jt][r] * inv[r] * fm;
            const int lrow = w * 16 + g * 4 + r;
            *(unsigned short*)((char*)ps + lrow * 256 +
                (((j >> 3) ^ (lrow & 7)) << 4) + (j & 7) * 2) = f2bfu(p);
        }
    }

    // ---- AO^T[l][c] = att[l][:] x v[c][:] ----
    f32x4 ao[4];
#pragma unroll
    for (int ct = 0; ct < 4; ++ct) ao[ct] = (f32x4){0.f, 0.f, 0.f, 0.f};
#pragma unroll
    for (int ks = 0; ks < 4; ++ks) {
        const int arow = w * 16 + l15;
        const int aq_ = ks * 4 + g;
        const bf16x8 pa = *(const bf16x8*)((char*)ps + arow * 256 + ((aq_ ^ (arow & 7)) << 4));
#pragma unroll
        for (int ct = 0; ct < 4; ++ct) {
            const int vrow = ct * 16 + l15;
            const bf16x8 vb = *(const bf16x8*)((char*)vs + vrow * 256 + ((aq_ ^ (vrow & 7)) << 4));
            ao[ct] = mfma16(pa, vb, ao[ct]);
        }
    }
#pragma unroll
    for (int ct = 0; ct < 4; ++ct)
#pragma unroll
        for (int r = 0; r < 4; ++r) {
            const int lr = w * 16 + g * 4 + r;
            const int c  = ct * 16 + l15;
            *(unsigned short*)((char*)aos + lr * 128 +
                (((c >> 3) ^ (lr & 7)) << 4) + (c & 7) * 2) = f2bfu(fmaxf(ao[ct][r], 0.f));
        }
    __syncthreads();

    // ---- out = Wo @ relu(AO) + bo, * mask (NONTEMPORAL stores) ----
    f32x4 mvv;
#pragma unroll
    for (int lt = 0; lt < 4; ++lt)
        mvv[lt] = mask[(size_t)b * L + n * 64 + lt * 16 + l15];

    bf16x8 bbs[8];
#pragma unroll
    for (int ks = 0; ks < 2; ++ks)
#pragma unroll
        for (int lt = 0; lt < 4; ++lt) {
            const int brow = lt * 16 + l15;
            bbs[ks * 4 + lt] = *(const bf16x8*)((char*)aos + brow * 128 +
                (((ks * 4 + g) ^ (brow & 7)) << 4));
        }

#pragma unroll 1
    for (int ot = 0; ot < 4; ++ot) {
        const int orow = ot * 64 + w * 16 + l15;
        bf16x8 wa[2];
#pragma unroll
        for (int ks = 0; ks < 2; ++ks)
            wa[ks] = *(const bf16x8*)(wob + (size_t)orow * 64 + ks * 32 + g * 8);
        f32x4 acw[4];
#pragma unroll
        for (int lt = 0; lt < 4; ++lt) acw[lt] = (f32x4){0.f, 0.f, 0.f, 0.f};
#pragma unroll
        for (int ks = 0; ks < 2; ++ks)
#pragma unroll
            for (int lt = 0; lt < 4; ++lt)
                acw[lt] = mfma16(wa[ks], bbs[ks * 4 + lt], acw[lt]);
        const f32x4 bo4 = *(const f32x4*)(bo + ot * 64 + w * 16 + g * 4);
#pragma unroll
        for (int lt = 0; lt < 4; ++lt) {
            const int pos = n * 64 + lt * 16 + l15;
#pragma unroll
            for (int r = 0; r < 4; ++r) {
                const int o = ot * 64 + w * 16 + g * 4 + r;
                __builtin_nontemporal_store(
                    (acw[lt][r] + bo4[r]) * mvv[lt],
                    &outp[((size_t)b * C + o) * L + pos]);
            }
        }
    }
}

// ---------------------------------------------------------------------------
extern "C" void kernel_launch(void* const* d_in, const int* in_sizes, int n_in,
                              void* d_out, int out_size, void* d_ws, size_t ws_size,
                              hipStream_t stream) {
    const float* x1   = (const float*)d_in[0];
    const float* x2   = (const float*)d_in[1];
    const float* mask = (const float*)d_in[2];
    const float* Wq   = (const float*)d_in[3];
    const float* bq   = (const float*)d_in[4];
    const float* Wk   = (const float*)d_in[5];
    const float* bk   = (const float*)d_in[6];
    const float* Wv   = (const float*)d_in[7];
    const float* bv   = (const float*)d_in[8];
    const float* Wo   = (const float*)d_in[9];
    const float* bo   = (const float*)d_in[10];
    float* out = (float*)d_out;

    unsigned short* ws = (unsigned short*)d_ws;
    const size_t PL = (size_t)B * L * CH;
    unsigned short* qt = ws;
    unsigned short* kt = qt + PL;
    unsigned short* vt = kt + PL;
    unsigned short* wb = vt + PL;   // [4][16384] bf16 weights
    const size_t need = (3 * PL + 4 * 16384) * sizeof(unsigned short);
    if (ws_size < need) {
        (void)hipMemsetAsync(d_out, 0, (size_t)out_size * sizeof(float), stream);
        return;
    }

    wcvt_kernel<<<dim3(16, 4), 256, 0, stream>>>(Wq, Wk, Wv, Wo, wb);

    qkv_mfma<<<dim3(L / 256, B), 256, 0, stream>>>(
        x1, x2, wb, wb + 16384, wb + 2 * 16384, bq, bk, bv, qt, kt, vt);

    attn_mfma<<<dim3(NB * B), 256, 0, stream>>>(
        qt, kt, vt, mask, wb + 3 * 16384, bo, out);
}